// Round 12
// baseline (75.432 us; speedup 1.0000x reference)
//
#include <hip/hip_runtime.h>

// Fused tanh-RNN (T=64, I=64, H=100) + tanh + linear (C=40), B=16384.
// TRANSPOSED formulation, interleaved-phi f16 weights (pkrtz-packable).
//
// Round-12: 4-WAVE N-SPLIT. Model fitted to 9 null rounds: solo-wave MFMA
// issue-to-issue ~58 cyc (no intra-wave pipelining); 42x58x64 = 65.0us =
// measured. Fix = more MFMA-issuing waves/SIMD: 4 waves per 16-row tile,
// roles own nt {0,1 | 2,3 | 4,5 | 6} (12/12/12/6 MFMAs/step). h exchanged
// through ONE 4KB LDS buffer: 1 ds_write_b128 + 2 barriers per step; with
// 4 independent blocks/CU the barrier stalls overlap across blocks.
// x slab-ring DMA split 4 ways (4x 1KB issues/wave/slab, counted vmcnt(4)).
// LDS 38912 -> 4 blocks/CU; launch_bounds(256,4) -> 128 VGPR (fc weights
// loaded only in the epilogue to keep the loop-live set ~124).

typedef _Float16 half8 __attribute__((ext_vector_type(8)));
typedef float float4_t __attribute__((ext_vector_type(4)));
typedef unsigned int uint4_t __attribute__((ext_vector_type(4)));

#define ROW_BYTES 1088                  // 1024 data + 64 pad
#define BUF_BYTES (16 * ROW_BYTES)      // 17408 per slab buffer
#define RING_BYTES (2 * BUF_BYTES)      // 34816
#define LDS_TOTAL (RING_BYTES + 4096)   // + single h buffer = 38912

#define GLOAD16(gp, lp)                                                   \
  __builtin_amdgcn_global_load_lds(                                       \
      (const __attribute__((address_space(1))) void*)(gp),                \
      (__attribute__((address_space(3))) void*)(lp), 16, 0, 0)

__device__ __forceinline__ float tanh_fast(float x) {
  float e = __builtin_amdgcn_exp2f(x * 2.8853900817779268f);
  return 1.0f - 2.0f * __builtin_amdgcn_rcpf(e + 1.0f);
}
__device__ __forceinline__ unsigned int pk2(float lo, float hi) {
  return __builtin_bit_cast(unsigned int, __builtin_amdgcn_cvt_pkrtz(lo, hi));
}
__device__ __forceinline__ half8 pack4(unsigned int a, unsigned int b,
                                       unsigned int c, unsigned int d) {
  uint4_t u = {a, b, c, d};
  return __builtin_bit_cast(half8, u);
}

template <int R, int NTN>
__device__ __forceinline__ void run_role(
    const float* __restrict__ x, const float* __restrict__ W_ih,
    const float* __restrict__ W_hh, const float* __restrict__ b_ih,
    const float* __restrict__ b_hh, const float* __restrict__ fc_W,
    const float* __restrict__ fc_b, float* __restrict__ out,
    int rowbase, int lane, char* lds)
{
  const int g = lane >> 4;
  const int c = lane & 15;

  // ---- x slab DMA (rows 4R..4R+3 of the tile), issued before weight loads
  const float* dsrc = x + (size_t)(rowbase + 4 * R) * 4096 + lane * 4;
  {
    #pragma unroll
    for (int s = 0; s < 2; ++s)
      #pragma unroll
      for (int j = 0; j < 4; ++j)
        GLOAD16(dsrc + j * 4096 + s * 256,
                lds + s * BUF_BYTES + (4 * R + j) * ROW_BYTES);
  }

  // ---- weights for this role's nt set (interleaved phi placement)
  half8 whh[4][NTN];
  half8 wih[2][NTN];
  float4_t bias[NTN];
  #pragma unroll
  for (int nl = 0; nl < NTN; ++nl) {
    int nt = 2 * R + nl;
    int nb = nt * 16 + 4 * g;
    float4_t bi = {0.f, 0.f, 0.f, 0.f};
    if (nb + 3 < 100) {
      float4_t a = *(const float4_t*)(b_ih + nb);
      float4_t b = *(const float4_t*)(b_hh + nb);
      bi = a + b;
    }
    bias[nl] = bi;

    int nrow = nt * 16 + c;
    bool rv = (nrow < 100);
    #pragma unroll
    for (int kb = 0; kb < 2; ++kb) {
      float4_t f0 = {0.f,0.f,0.f,0.f}, f1 = {0.f,0.f,0.f,0.f};
      if (rv) {
        const float* p = W_ih + nrow * 64 + kb * 32 + g * 8;
        f0 = *(const float4_t*)p;
        f1 = *(const float4_t*)(p + 4);
      }
      half8 h;
      #pragma unroll
      for (int j = 0; j < 4; ++j) { h[2*j] = (_Float16)f0[j]; h[2*j+1] = (_Float16)f1[j]; }
      wih[kb][nl] = h;
    }
    #pragma unroll
    for (int kb = 0; kb < 4; ++kb) {
      int clo = kb * 32 + 4 * g;
      int chi = clo + 16;
      float4_t f0 = {0.f,0.f,0.f,0.f}, f1 = {0.f,0.f,0.f,0.f};
      if (rv && clo + 3 < 100) f0 = *(const float4_t*)(W_hh + nrow * 100 + clo);
      if (rv && chi + 3 < 100) f1 = *(const float4_t*)(W_hh + nrow * 100 + chi);
      half8 h;
      #pragma unroll
      for (int j = 0; j < 4; ++j) { h[2*j] = (_Float16)f0[j]; h[2*j+1] = (_Float16)f1[j]; }
      whh[kb][nl] = h;
    }
  }

  const unsigned lbase =
      (unsigned)(uintptr_t)(__attribute__((address_space(3))) char*)lds;
  const unsigned xbase = lbase + (unsigned)(c * ROW_BYTES + g * 32);
  const unsigned hbase = lbase + RING_BYTES + (unsigned)(c * 64 + g * 16);
  const unsigned hw = hbase + R * 1024;   // own frag slot

  // ---- h_0 = 0: publish own zero frag; slab 0 landed; sync
  half8 own_hf = (half8)(_Float16)0.0f;
  {
    float4_t z = {0.f, 0.f, 0.f, 0.f};
    asm volatile("ds_write_b128 %0, %1" :: "v"(hw), "v"(z) : "memory");
  }
  asm volatile("s_waitcnt vmcnt(4) lgkmcnt(0)\n\ts_barrier" ::: "memory");

  float4_t acc[NTN];

  for (int grp = 0; grp < 16; ++grp) {
    unsigned xg = xbase + (unsigned)((grp & 1) * BUF_BYTES);
    #pragma unroll
    for (int t4 = 0; t4 < 4; ++t4) {
      // issue reads: x fragment + all 4 h frags (own read unused)
      unsigned xs = xg + (unsigned)(t4 * 256);
      float4_t s0, s1, s2, s3, f0, f1, f2, f3;
      asm volatile(
          "ds_read_b128 %0, %4 offset:0\n\t"
          "ds_read_b128 %1, %4 offset:16\n\t"
          "ds_read_b128 %2, %4 offset:128\n\t"
          "ds_read_b128 %3, %4 offset:144"
          : "=&v"(s0), "=&v"(s1), "=&v"(s2), "=&v"(s3)
          : "v"(xs) : "memory");
      asm volatile(
          "ds_read_b128 %0, %4 offset:0\n\t"
          "ds_read_b128 %1, %4 offset:1024\n\t"
          "ds_read_b128 %2, %4 offset:2048\n\t"
          "ds_read_b128 %3, %4 offset:3072"
          : "=&v"(f0), "=&v"(f1), "=&v"(f2), "=&v"(f3)
          : "v"(hbase) : "memory");

      // own-kb rung from registers while reads are in flight
      #pragma unroll
      for (int nl = 0; nl < NTN; ++nl)
        acc[nl] = __builtin_amdgcn_mfma_f32_16x16x32_f16(whh[R][nl], own_hf, bias[nl], 0, 0, 0);

      asm volatile("s_waitcnt lgkmcnt(0)"
                   : "+v"(s0), "+v"(s1), "+v"(s2), "+v"(s3),
                     "+v"(f0), "+v"(f1), "+v"(f2), "+v"(f3) :: "memory");
      __builtin_amdgcn_sched_barrier(0);

      half8 hfr[4] = {__builtin_bit_cast(half8, f0), __builtin_bit_cast(half8, f1),
                      __builtin_bit_cast(half8, f2), __builtin_bit_cast(half8, f3)};
      #pragma unroll
      for (int kb = 0; kb < 4; ++kb)
        if (kb != R)
          #pragma unroll
          for (int nl = 0; nl < NTN; ++nl)
            acc[nl] = __builtin_amdgcn_mfma_f32_16x16x32_f16(whh[kb][nl], hfr[kb], acc[nl], 0, 0, 0);

      half8 xb0 = pack4(pk2(s0[0], s1[0]), pk2(s0[1], s1[1]),
                        pk2(s0[2], s1[2]), pk2(s0[3], s1[3]));
      half8 xb1 = pack4(pk2(s2[0], s3[0]), pk2(s2[1], s3[1]),
                        pk2(s2[2], s3[2]), pk2(s2[3], s3[3]));
      #pragma unroll
      for (int nl = 0; nl < NTN; ++nl) {
        acc[nl] = __builtin_amdgcn_mfma_f32_16x16x32_f16(wih[0][nl], xb0, acc[nl], 0, 0, 0);
        acc[nl] = __builtin_amdgcn_mfma_f32_16x16x32_f16(wih[1][nl], xb1, acc[nl], 0, 0, 0);
      }

      // h_{t+1} own slice = tanh(preact); pack own frag
      #pragma unroll
      for (int nl = 0; nl < NTN; ++nl)
        #pragma unroll
        for (int v = 0; v < 4; ++v)
          acc[nl][v] = tanh_fast(acc[nl][v]);
      if (NTN == 2)
        own_hf = pack4(pk2(acc[0][0], acc[1][0]), pk2(acc[0][1], acc[1][1]),
                       pk2(acc[0][2], acc[1][2]), pk2(acc[0][3], acc[1][3]));
      else
        own_hf = pack4(pk2(acc[0][0], 0.0f), pk2(acc[0][1], 0.0f),
                       pk2(acc[0][2], 0.0f), pk2(acc[0][3], 0.0f));

      // barrier A: everyone finished reading h_t; then publish h_{t+1}
      asm volatile("s_barrier" ::: "memory");
      asm volatile("ds_write_b128 %0, %1"
                   :: "v"(hw), "v"(__builtin_bit_cast(float4_t, own_hf)) : "memory");

      if (t4 == 3) {
        int sl = grp + 2; if (sl > 15) sl = 15;
        #pragma unroll
        for (int j = 0; j < 4; ++j)
          GLOAD16(dsrc + j * 4096 + sl * 256,
                  lds + (sl & 1) * BUF_BYTES + (4 * R + j) * ROW_BYTES);
        asm volatile("s_waitcnt vmcnt(4) lgkmcnt(0)\n\ts_barrier" ::: "memory");  // B
      } else {
        asm volatile("s_waitcnt lgkmcnt(0)\n\ts_barrier" ::: "memory");           // B
      }
    }
  }

  // ---- epilogue: z = tanh(h_64); publish zf frag; fc GEMM on roles 0..2
  #pragma unroll
  for (int nl = 0; nl < NTN; ++nl)
    #pragma unroll
    for (int v = 0; v < 4; ++v)
      acc[nl][v] = tanh_fast(acc[nl][v]);
  half8 zf_own;
  if (NTN == 2)
    zf_own = pack4(pk2(acc[0][0], acc[1][0]), pk2(acc[0][1], acc[1][1]),
                   pk2(acc[0][2], acc[1][2]), pk2(acc[0][3], acc[1][3]));
  else
    zf_own = pack4(pk2(acc[0][0], 0.0f), pk2(acc[0][1], 0.0f),
                   pk2(acc[0][2], 0.0f), pk2(acc[0][3], 0.0f));
  asm volatile("ds_write_b128 %0, %1"
               :: "v"(hw), "v"(__builtin_bit_cast(float4_t, zf_own)) : "memory");
  asm volatile("s_waitcnt lgkmcnt(0)\n\ts_barrier" ::: "memory");

  if (R < 3) {
    // fc weights loaded HERE (epilogue-only) to keep loop VGPR under 128
    half8 wfc[4];
    float4_t bfc = {0.f, 0.f, 0.f, 0.f};
    {
      int nb = R * 16 + 4 * g;
      if (nb + 3 < 40) bfc = *(const float4_t*)(fc_b + nb);
      int nrow = R * 16 + c;
      bool rv = (nrow < 40);
      #pragma unroll
      for (int kb = 0; kb < 4; ++kb) {
        int clo = kb * 32 + 4 * g;
        int chi = clo + 16;
        float4_t f0 = {0.f,0.f,0.f,0.f}, f1 = {0.f,0.f,0.f,0.f};
        if (rv && clo + 3 < 100) f0 = *(const float4_t*)(fc_W + nrow * 100 + clo);
        if (rv && chi + 3 < 100) f1 = *(const float4_t*)(fc_W + nrow * 100 + chi);
        half8 h;
        #pragma unroll
        for (int j = 0; j < 4; ++j) { h[2*j] = (_Float16)f0[j]; h[2*j+1] = (_Float16)f1[j]; }
        wfc[kb] = h;
      }
    }
    float4_t z0, z1, z2, z3;
    asm volatile(
        "ds_read_b128 %0, %4 offset:0\n\t"
        "ds_read_b128 %1, %4 offset:1024\n\t"
        "ds_read_b128 %2, %4 offset:2048\n\t"
        "ds_read_b128 %3, %4 offset:3072\n\t"
        "s_waitcnt lgkmcnt(0)"
        : "=&v"(z0), "=&v"(z1), "=&v"(z2), "=&v"(z3)
        : "v"(hbase) : "memory");
    __builtin_amdgcn_sched_barrier(0);
    half8 zf[4] = {__builtin_bit_cast(half8, z0), __builtin_bit_cast(half8, z1),
                   __builtin_bit_cast(half8, z2), __builtin_bit_cast(half8, z3)};
    float4_t oacc = __builtin_amdgcn_mfma_f32_16x16x32_f16(wfc[0], zf[0], bfc, 0, 0, 0);
    #pragma unroll
    for (int kb = 1; kb < 4; ++kb)
      oacc = __builtin_amdgcn_mfma_f32_16x16x32_f16(wfc[kb], zf[kb], oacc, 0, 0, 0);

    #pragma unroll
    for (int v = 0; v < 4; ++v) {
      int n = R * 16 + 4 * g + v;
      if (n < 40)
        out[(size_t)(rowbase + c) * 40 + n] = oacc[v];
    }
  }
}

__global__ __launch_bounds__(256, 4) void rnn_fused(
    const float* __restrict__ x, const float* __restrict__ W_ih,
    const float* __restrict__ W_hh, const float* __restrict__ b_ih,
    const float* __restrict__ b_hh, const float* __restrict__ fc_W,
    const float* __restrict__ fc_b, float* __restrict__ out, int B)
{
  __shared__ char lds[LDS_TOTAL];
  const int lane = threadIdx.x & 63;
  const int wave = threadIdx.x >> 6;
  const int rowbase = blockIdx.x * 16;
  if (rowbase >= B) return;

  if (wave == 0)
    run_role<0, 2>(x, W_ih, W_hh, b_ih, b_hh, fc_W, fc_b, out, rowbase, lane, lds);
  else if (wave == 1)
    run_role<1, 2>(x, W_ih, W_hh, b_ih, b_hh, fc_W, fc_b, out, rowbase, lane, lds);
  else if (wave == 2)
    run_role<2, 2>(x, W_ih, W_hh, b_ih, b_hh, fc_W, fc_b, out, rowbase, lane, lds);
  else
    run_role<3, 1>(x, W_ih, W_hh, b_ih, b_hh, fc_W, fc_b, out, rowbase, lane, lds);
}

extern "C" void kernel_launch(void* const* d_in, const int* in_sizes, int n_in,
                              void* d_out, int out_size, void* d_ws, size_t ws_size,
                              hipStream_t stream) {
  const float* x    = (const float*)d_in[0];
  const float* W_ih = (const float*)d_in[1];
  const float* W_hh = (const float*)d_in[2];
  const float* b_ih = (const float*)d_in[3];
  const float* b_hh = (const float*)d_in[4];
  const float* fc_W = (const float*)d_in[5];
  const float* fc_b = (const float*)d_in[6];
  float* outp = (float*)d_out;

  int B = in_sizes[0] / 4096;      // 16384
  int grid = (B + 15) / 16;        // one 16-row tile per 4-wave block
  rnn_fused<<<grid, 256, 0, stream>>>(x, W_ih, W_hh, b_ih, b_hh, fc_W, fc_b, outp, B);
}